// Round 6
// baseline (29666.629 us; speedup 1.0000x reference)
//
#include <hip/hip_runtime.h>
#include <hip/hip_bf16.h>

#define B_SZ 1024
#define T_ENC 384
#define T_DEC 128
#define I_SZ 128
#define H_SZ 512

typedef __attribute__((ext_vector_type(8))) short short8;
typedef __attribute__((ext_vector_type(4))) float floatx4;
typedef unsigned short ushort_t;
typedef unsigned long long u64;

__device__ __forceinline__ ushort_t f2bf(float x) {
    union { float f; unsigned int i; } v; v.f = x;
    unsigned int u = v.i;
    unsigned int r = (u + 0x7fffu + ((u >> 16) & 1u)) >> 16;
    return (ushort_t)r;
}
__device__ __forceinline__ float sigm(float x) { return 1.0f / (1.0f + __expf(-x)); }

// agent-coherent 8B load (bypasses possibly-stale per-XCD L2; served at coherence point)
__device__ __forceinline__ u64 ald8(const ushort_t* p) {
    return __hip_atomic_load((const u64*)(const void*)p, __ATOMIC_RELAXED, __HIP_MEMORY_SCOPE_AGENT);
}

// Bounded relaxed spin with fence fallback (hang-proof; fallback never fires when the
// relaxed-visibility model holds — validated round 4).
__device__ __forceinline__ void spin_ge(unsigned* p, unsigned tgt) {
    int n = 0;
    while (__hip_atomic_load(p, __ATOMIC_RELAXED, __HIP_MEMORY_SCOPE_AGENT) < tgt) {
        __builtin_amdgcn_s_sleep(1);
        if (++n == (1 << 13)) { __threadfence(); n = 0; }
    }
}

// Fence-free monotone tree barrier (validated round 4: correct, no L2 invalidation).
#define BLINE 64   // u32 per line (256B)
__device__ __forceinline__ void gbar(unsigned* bar, int bid, int nb, unsigned& step) {
    asm volatile("s_waitcnt vmcnt(0) lgkmcnt(0)" ::: "memory");   // all waves: publish h
    __syncthreads();
    if (threadIdx.x == 0) {
        const unsigned s1 = step + 1;
        const int grp = bid >> 3;
        const unsigned ngrp = (unsigned)(nb >> 3);
        unsigned* gcnt = bar + (size_t)grp * BLINE;
        unsigned* gsig = gcnt + 1;
        unsigned* rcnt = bar + (size_t)ngrp * BLINE;
        unsigned old = __hip_atomic_fetch_add(gcnt, 1u, __ATOMIC_RELAXED, __HIP_MEMORY_SCOPE_AGENT);
        if (old == 8u * s1 - 1u) {            // last arrival of this group
            unsigned rold = __hip_atomic_fetch_add(rcnt, 1u, __ATOMIC_RELAXED, __HIP_MEMORY_SCOPE_AGENT);
            if (rold != ngrp * s1 - 1u)
                spin_ge(rcnt, ngrp * s1);
            __hip_atomic_store(gsig, s1, __ATOMIC_RELAXED, __HIP_MEMORY_SCOPE_AGENT);
        } else {
            spin_ge(gsig, s1);
        }
    }
    step += 1;
    __syncthreads();
}

// fp32 -> bf16 bulk convert (weights, once per launch). n % 1024 == 0.
__global__ __launch_bounds__(256) void cvt_f32_bf16(
    const float* __restrict__ src, ushort_t* __restrict__ dst, int n)
{
    int i = (blockIdx.x * 256 + threadIdx.x) * 4;
    if (i < n) {
        float4 v = *(const float4*)(src + i);
        short4 s = { (short)f2bf(v.x), (short)f2bf(v.y), (short)f2bf(v.z), (short)f2bf(v.w) };
        *(short4*)(dst + i) = s;
    }
}

// dec_in(t=0) = bf16(x[:, -1, :])
__global__ void copy_last(const float* __restrict__ x, ushort_t* __restrict__ dst)
{
    int i = blockIdx.x * 256 + threadIdx.x;           // 0 .. 131071
    int b = i >> 7, k = i & 127;
    dst[i] = f2bf(x[((size_t)b * T_ENC + (T_ENC - 1)) * I_SZ + k]);
}

#define BM 64
#define BN 32
#define KC 64
#define LDSW (KC + 8)    // 72 shorts: 144B row stride, 16B-aligned, breaks bank stride
#define DLW  (I_SZ + 8)  // 136 shorts: DecIn stride

// XCD-aware swizzle: pin 2 col-groups per XCD so each XCD's weight slice (~832 KB)
// stays L2-resident across the persistent run.
__device__ __forceinline__ void tile_of(int bid, int& row0, int& col0) {
    int xcd = bid & 7, q = bid >> 3;          // q in [0,32)
    int cgp = xcd * 2 + (q & 1);              // col-group 0..15
    int rg = q >> 1;                          // row-group 0..15
    row0 = rg * BM; col0 = cgp * BN;
}

__device__ __forceinline__ void load_bias(
    const float* bih, const float* bhh, int col0, int l15, float (&bs)[4][2])
{
#pragma unroll
    for (int g = 0; g < 4; ++g)
#pragma unroll
        for (int n = 0; n < 2; ++n) {
            int gcol = col0 + n * 16 + l15;
            bs[g][n] = bih[g * H_SZ + gcol] + bhh[g * H_SZ + gcol];
        }
}

// One LSTM cell step for a 64row x (4 gates x 32)col tile; c and biases in registers.
// AMODE: 0 = A1 bf16 global h-buffer (agent loads), 1 = A1 fp32 global x (NT loads),
//        2 = A1 in LDS (DecIn, stride DLW).
// Register-prefetch double buffering: kb+1's global loads are issued between the two
// barriers of kb and land in VGPRs while kb's MFMAs run; single LDS buffer.
// Weights: plain cached loads (stay L2-resident — x is NT, h bypasses L2).
template<int AMODE>
__device__ __forceinline__ void cell_step(
    int row0, int col0,
    const void* A1v, int lda1, int K1,
    const ushort_t* W1, const ushort_t* A2, const ushort_t* W2,
    const float (&bs)[4][2], float (&creg)[2][4],
    ushort_t* h_out, short* As, short* Ws)
{
    const int tid  = threadIdx.x;
    const int wave = tid >> 6;
    const int lane = tid & 63;
    const int quad = lane >> 4;
    const int l15  = lane & 15;
    const int sr   = tid >> 3;     // staging row 0..31 (+32 for second half)
    const int scch = tid & 7;      // staging 16B chunk

    floatx4 acc[4][2];
#pragma unroll
    for (int g = 0; g < 4; ++g)
#pragma unroll
        for (int n = 0; n < 2; ++n)
            acc[g][n] = (floatx4){0.f, 0.f, 0.f, 0.f};

    u64 aR[4];        // h-path prefetch regs (2 x 16B)
    floatx4 xF[4];    // x-path prefetch regs (AMODE 1, kb < K1)
    int4 wR[4];       // W prefetch regs (4 x 16B)

    auto loadA = [&](int kb) {
        if (AMODE == 1 && kb < K1) {
            const float* af = (const float*)A1v + kb;
#pragma unroll
            for (int it = 0; it < 4; ++it) {
                int r = (tid >> 4) + it * 16;
                xF[it] = __builtin_nontemporal_load(
                    (const floatx4*)(const void*)(af + (size_t)(row0 + r) * lda1 + (tid & 15) * 4));
            }
        } else {
            const ushort_t* ab; int ald;
            if (kb < K1) { ab = (const ushort_t*)A1v + kb; ald = lda1; }
            else         { ab = A2 + (kb - K1);            ald = H_SZ; }
#pragma unroll
            for (int it = 0; it < 2; ++it) {
                int r = sr + it * 32;
                const ushort_t* s = ab + (size_t)(row0 + r) * ald + scch * 8;
                aR[it * 2 + 0] = ald8(s);
                aR[it * 2 + 1] = ald8(s + 4);
            }
        }
    };
    auto loadW = [&](int kb) {
        const ushort_t* wsrc; int wld;
        if (kb < K1) { wsrc = W1 + kb;        wld = K1;  }
        else         { wsrc = W2 + (kb - K1); wld = H_SZ; }
#pragma unroll
        for (int g = 0; g < 4; ++g)
            wR[g] = *(const int4*)(const void*)(wsrc + (size_t)(g * H_SZ + col0 + sr) * wld + scch * 8);
    };

    const int KT = K1 + H_SZ;
    if (AMODE != 2) loadA(0);
    loadW(0);

    for (int kb = 0; kb < KT; kb += KC) {
        // ---- ds_write current prefetched regs ----
        if (AMODE == 1 && kb < K1) {
#pragma unroll
            for (int it = 0; it < 4; ++it) {
                int r = (tid >> 4) + it * 16;
                short4 s = { (short)f2bf(xF[it].x), (short)f2bf(xF[it].y),
                             (short)f2bf(xF[it].z), (short)f2bf(xF[it].w) };
                *(short4*)(void*)&As[r * LDSW + (tid & 15) * 4] = s;
            }
        } else if (!(AMODE == 2 && kb < K1)) {
#pragma unroll
            for (int it = 0; it < 2; ++it) {
                int r = sr + it * 32;
                u64* d = (u64*)(void*)&As[r * LDSW + scch * 8];
                d[0] = aR[it * 2 + 0]; d[1] = aR[it * 2 + 1];
            }
        }
#pragma unroll
        for (int g = 0; g < 4; ++g)
            *(int4*)(void*)&Ws[(g * 32 + sr) * LDSW + scch * 8] = wR[g];
        __syncthreads();

        // ---- issue next-kb global loads (overlap with MFMA below) ----
        const int kbn = kb + KC;
        if (kbn < KT) {
            if (!(AMODE == 2 && kbn < K1)) loadA(kbn);
            loadW(kbn);
        }

        // ---- compute current kb from LDS ----
#pragma unroll
        for (int ks = 0; ks < 2; ++ks) {
            const int ko = ks * 32 + quad * 8;
            short8 a;
            if (AMODE == 2 && kb < K1)
                a = *(const short8*)(const void*)&((const short*)A1v)[(wave * 16 + l15) * DLW + kb + ko];
            else
                a = *(const short8*)(const void*)&As[(wave * 16 + l15) * LDSW + ko];
#pragma unroll
            for (int g = 0; g < 4; ++g)
#pragma unroll
                for (int n = 0; n < 2; ++n) {
                    short8 b = *(const short8*)(const void*)&Ws[(g * BN + n * 16 + l15) * LDSW + ko];
                    acc[g][n] = __builtin_amdgcn_mfma_f32_16x16x32_bf16(a, b, acc[g][n], 0, 0, 0);
                }
        }
        __syncthreads();
    }

#pragma unroll
    for (int n = 0; n < 2; ++n) {
        const int gcol = col0 + n * 16 + l15;
#pragma unroll
        for (int r = 0; r < 4; ++r) {
            const int grow = row0 + wave * 16 + quad * 4 + r;
            const float zi = acc[0][n][r] + bs[0][n];
            const float zf = acc[1][n][r] + bs[1][n];
            const float zg = acc[2][n][r] + bs[2][n];
            const float zo = acc[3][n][r] + bs[3][n];
            const float cn = sigm(zf) * creg[n][r] + sigm(zi) * tanhf(zg);
            creg[n][r] = cn;
            const float hv = sigm(zo) * tanhf(cn);
            const float hnb = __shfl_xor(hv, 1);
            if ((lane & 1) == 0) {   // paired lanes: one 32-bit agent store per 2 cols
                unsigned p = (unsigned)f2bf(hv) | ((unsigned)f2bf(hnb) << 16);
                __hip_atomic_store((unsigned*)(void*)&h_out[(size_t)grow * H_SZ + gcol],
                                   p, __ATOMIC_RELAXED, __HIP_MEMORY_SCOPE_AGENT);
            }
        }
    }
}

// Persistent encoder: 512 blocks (2/CU, all resident).
// Blocks 0..255: L0(t) for t=0..383.  Blocks 256..511: L1(t-1) for t=1..384.
__global__ __launch_bounds__(256, 2) void enc_persist(
    const float* x,
    const ushort_t* Wih0, const ushort_t* Whh0, const float* bih0, const float* bhh0,
    const ushort_t* Wih1, const ushort_t* Whh1, const float* bih1, const float* bhh1,
    ushort_t* h0a, ushort_t* h0b, ushort_t* h1a, ushort_t* h1b,
    float* c0, float* c1, unsigned* bar)
{
    __shared__ short As[BM * LDSW];
    __shared__ short Ws[4 * BN * LDSW];

    const int tid = threadIdx.x;
    const int bid = blockIdx.x;
    const bool isL0 = (bid < 256);
    int row0, col0; tile_of(isL0 ? bid : (bid - 256), row0, col0);
    const int lane = tid & 63, l15 = lane & 15, quad = lane >> 4, wave = tid >> 6;

    float bs[4][2];
    load_bias(isL0 ? bih0 : bih1, isL0 ? bhh0 : bhh1, col0, l15, bs);
    float creg[2][4];
#pragma unroll
    for (int n = 0; n < 2; ++n)
#pragma unroll
        for (int r = 0; r < 4; ++r) creg[n][r] = 0.f;

    ushort_t *h0c = h0a, *h0n = h0b, *h1c = h1a, *h1n = h1b;
    unsigned step = 0;

    for (int t = 0; t <= T_ENC; ++t) {
        if (isL0) {
            if (t < T_ENC)
                cell_step<1>(row0, col0, x + (size_t)t * I_SZ, T_ENC * I_SZ, I_SZ,
                             Wih0, h0c, Whh0, bs, creg, h0n, As, Ws);
        } else {
            if (t > 0)
                cell_step<0>(row0, col0, h0c, H_SZ, H_SZ,
                             Wih1, h1c, Whh1, bs, creg, h1n, As, Ws);
        }
        gbar(bar, bid, 512, step);
        if (t < T_ENC) { ushort_t* tmp = h0c; h0c = h0n; h0n = tmp; }
        if (t > 0)     { ushort_t* tmp = h1c; h1c = h1n; h1n = tmp; }
    }
    // final c states for the decoder (kernel boundary publishes them)
    float* cdst = isL0 ? c0 : c1;
#pragma unroll
    for (int n = 0; n < 2; ++n)
#pragma unroll
        for (int r = 0; r < 4; ++r) {
            int grow = row0 + wave * 16 + quad * 4 + r;
            int gcol = col0 + n * 16 + l15;
            cdst[(size_t)grow * H_SZ + gcol] = creg[n][r];
        }
}

// Persistent decoder: 256 blocks (all resident). Each block owns the same (rg,cg)
// tile of BOTH layers; c0/c1 tiles live in registers the whole run.
// Per step t: [fc(t-1)+out + L0(t)]  barrier  [L1(t)]  barrier.
__global__ __launch_bounds__(256, 2) void dec_persist(
    const ushort_t* dec0, const ushort_t* fcw, const float* fcb, float* out,
    const ushort_t* Wih0, const ushort_t* Whh0, const float* bih0, const float* bhh0,
    const ushort_t* Wih1, const ushort_t* Whh1, const float* bih1, const float* bhh1,
    ushort_t* h0a, ushort_t* h0b, ushort_t* h1a, ushort_t* h1b,
    const float* c0in, const float* c1in, unsigned* bar)
{
    __shared__ short As[BM * LDSW];
    __shared__ short Ws[4 * BN * LDSW];
    __shared__ short DecIn[BM * DLW];

    const int tid = threadIdx.x;
    const int wave = tid >> 6, lane = tid & 63, quad = lane >> 4, l15 = lane & 15;
    const int sr = tid >> 3, scch = tid & 7;
    int row0, col0; tile_of(blockIdx.x, row0, col0);
    const int cgrp = col0 / BN;

    float bs0[4][2], bs1[4][2];
    load_bias(bih0, bhh0, col0, l15, bs0);
    load_bias(bih1, bhh1, col0, l15, bs1);

    float c0reg[2][4], c1reg[2][4];
#pragma unroll
    for (int n = 0; n < 2; ++n)
#pragma unroll
        for (int r = 0; r < 4; ++r) {
            int grow = row0 + wave * 16 + quad * 4 + r;
            int gcol = col0 + n * 16 + l15;
            c0reg[n][r] = c0in[(size_t)grow * H_SZ + gcol];
            c1reg[n][r] = c1in[(size_t)grow * H_SZ + gcol];
        }

    ushort_t *h0c = h0a, *h0n = h0b, *h1c = h1a, *h1n = h1b;
    unsigned step = 0;

    for (int t = 0; t <= T_DEC; ++t) {
        // ---------- phase A: fc(t-1) -> DecIn (+ out(t-1)), then L0(t) ----------
        if (t > 0) {
            float* outp = out + (size_t)(t - 1) * I_SZ;
            floatx4 a2[8];
#pragma unroll
            for (int n = 0; n < 8; ++n) a2[n] = (floatx4){0.f, 0.f, 0.f, 0.f};

            u64 aR[4]; int4 wR[4];
            auto loadFA = [&](int kb) {
#pragma unroll
                for (int it = 0; it < 2; ++it) {
                    int r = sr + it * 32;
                    const ushort_t* s = h1c + (size_t)(row0 + r) * H_SZ + kb + scch * 8;
                    aR[it * 2 + 0] = ald8(s);
                    aR[it * 2 + 1] = ald8(s + 4);
                }
            };
            auto loadFW = [&](int kb) {
#pragma unroll
                for (int it = 0; it < 4; ++it)
                    wR[it] = *(const int4*)(const void*)(fcw + (size_t)(it * 32 + sr) * H_SZ + kb + scch * 8);
            };
            loadFA(0); loadFW(0);

            for (int kb = 0; kb < H_SZ; kb += KC) {
#pragma unroll
                for (int it = 0; it < 2; ++it) {
                    int r = sr + it * 32;
                    u64* d = (u64*)(void*)&As[r * LDSW + scch * 8];
                    d[0] = aR[it * 2 + 0]; d[1] = aR[it * 2 + 1];
                }
#pragma unroll
                for (int it = 0; it < 4; ++it)
                    *(int4*)(void*)&Ws[(it * 32 + sr) * LDSW + scch * 8] = wR[it];
                __syncthreads();

                int kbn = kb + KC;
                if (kbn < H_SZ) { loadFA(kbn); loadFW(kbn); }

#pragma unroll
                for (int ks = 0; ks < 2; ++ks) {
                    const int ko = ks * 32 + quad * 8;
                    short8 a = *(const short8*)(const void*)&As[(wave * 16 + l15) * LDSW + ko];
#pragma unroll
                    for (int n = 0; n < 8; ++n) {
                        short8 b = *(const short8*)(const void*)&Ws[(n * 16 + l15) * LDSW + ko];
                        a2[n] = __builtin_amdgcn_mfma_f32_16x16x32_bf16(a, b, a2[n], 0, 0, 0);
                    }
                }
                __syncthreads();
            }
#pragma unroll
            for (int n = 0; n < 8; ++n) {
                const int col = n * 16 + l15;
                const float bias = fcb[col];
#pragma unroll
                for (int r = 0; r < 4; ++r) {
                    const int lrow = wave * 16 + quad * 4 + r;
                    const float v = a2[n][r] + bias;
                    DecIn[lrow * DLW + col] = (short)f2bf(v);
                    if (cgrp == 0)
                        __builtin_nontemporal_store(v,
                            &outp[(size_t)(row0 + lrow) * T_DEC * I_SZ + col]);
                }
            }
        } else {
            // t==0: dec_in from global bf16 buffer (written by an earlier dispatch)
#pragma unroll
            for (int it = 0; it < 4; ++it) {
                int idx = tid + it * 256;              // 0..1023
                int r = idx >> 4, cch = idx & 15;
                int4 v = *(const int4*)(const void*)(dec0 + (size_t)(row0 + r) * I_SZ + cch * 8);
                *(int4*)(void*)&DecIn[r * DLW + cch * 8] = v;
            }
        }
        __syncthreads();

        if (t < T_DEC)
            cell_step<2>(row0, col0, (const void*)DecIn, DLW, I_SZ,
                         Wih0, h0c, Whh0, bs0, c0reg, h0n, As, Ws);
        gbar(bar, blockIdx.x, 256, step);

        // ---------- phase B: L1(t) ----------
        if (t < T_DEC) {
            cell_step<0>(row0, col0, h0n, H_SZ, H_SZ,
                         Wih1, h1c, Whh1, bs1, c1reg, h1n, As, Ws);
            gbar(bar, blockIdx.x, 256, step);
            { ushort_t* tmp = h0c; h0c = h0n; h0n = tmp; }
            { ushort_t* tmp = h1c; h1c = h1n; h1n = tmp; }
        }
    }
}

extern "C" void kernel_launch(void* const* d_in, const int* in_sizes, int n_in,
                              void* d_out, int out_size, void* d_ws, size_t ws_size,
                              hipStream_t stream)
{
    (void)in_sizes; (void)n_in; (void)out_size; (void)ws_size;
    const float* x     = (const float*)d_in[0];
    const float* W_ih0 = (const float*)d_in[1];
    const float* W_hh0 = (const float*)d_in[2];
    const float* b_ih0 = (const float*)d_in[3];
    const float* b_hh0 = (const float*)d_in[4];
    const float* W_ih1 = (const float*)d_in[5];
    const float* W_hh1 = (const float*)d_in[6];
    const float* b_ih1 = (const float*)d_in[7];
    const float* b_hh1 = (const float*)d_in[8];
    const float* fc_w  = (const float*)d_in[9];
    const float* fc_b  = (const float*)d_in[10];
    float* out = (float*)d_out;

    const int NW_IH0 = 4 * H_SZ * I_SZ;   // 262144
    const int NW_HH  = 4 * H_SZ * H_SZ;   // 1048576
    const int NW_FC  = I_SZ * H_SZ;       // 65536
    char* w = (char*)d_ws;
    ushort_t* wb_ih0 = (ushort_t*)w;  w += (size_t)NW_IH0 * 2;
    ushort_t* wb_hh0 = (ushort_t*)w;  w += (size_t)NW_HH  * 2;
    ushort_t* wb_ih1 = (ushort_t*)w;  w += (size_t)NW_HH  * 2;
    ushort_t* wb_hh1 = (ushort_t*)w;  w += (size_t)NW_HH  * 2;
    ushort_t* wb_fc  = (ushort_t*)w;  w += (size_t)NW_FC  * 2;
    const size_t HB2 = (size_t)B_SZ * H_SZ * 2;    // 1 MB bf16
    const size_t HB4 = (size_t)B_SZ * H_SZ * 4;    // 2 MB fp32
    ushort_t* h0a = (ushort_t*)w;  w += HB2;
    ushort_t* h0b = (ushort_t*)w;  w += HB2;
    ushort_t* h1a = (ushort_t*)w;  w += HB2;
    ushort_t* h1b = (ushort_t*)w;  w += HB2;
    float*    c0  = (float*)w;     w += HB4;
    float*    c1  = (float*)w;     w += HB4;
    ushort_t* dec0 = (ushort_t*)w; w += (size_t)B_SZ * I_SZ * 2;
    // barrier regions: enc = 64 groups + root = 65 lines; dec = 32 groups + root = 33
    unsigned* bar_enc = (unsigned*)w;              // 65 * 256B
    unsigned* bar_dec = bar_enc + 65 * 64;         // 33 * 256B
    const size_t BAR_BYTES = (65 + 33) * 256;
    w += BAR_BYTES;

    cvt_f32_bf16<<<NW_IH0 / 1024, 256, 0, stream>>>(W_ih0, wb_ih0, NW_IH0);
    cvt_f32_bf16<<<NW_HH  / 1024, 256, 0, stream>>>(W_hh0, wb_hh0, NW_HH);
    cvt_f32_bf16<<<NW_HH  / 1024, 256, 0, stream>>>(W_ih1, wb_ih1, NW_HH);
    cvt_f32_bf16<<<NW_HH  / 1024, 256, 0, stream>>>(W_hh1, wb_hh1, NW_HH);
    cvt_f32_bf16<<<NW_FC  / 1024, 256, 0, stream>>>(fc_w,  wb_fc,  NW_FC);

    hipMemsetAsync(h0a, 0, HB2, stream);
    hipMemsetAsync(h1a, 0, HB2, stream);
    hipMemsetAsync(bar_enc, 0, BAR_BYTES, stream);
    copy_last<<<512, 256, 0, stream>>>(x, dec0);

    // whole encoder: ONE launch, fence-free tree barrier between steps
    enc_persist<<<512, 256, 0, stream>>>(
        x, wb_ih0, wb_hh0, b_ih0, b_hh0,
        wb_ih1, wb_hh1, b_ih1, b_hh1,
        h0a, h0b, h1a, h1b, c0, c1, bar_enc);

    // whole decoder (incl. final fc): ONE launch
    dec_persist<<<256, 256, 0, stream>>>(
        dec0, wb_fc, fc_b, out,
        wb_ih0, wb_hh0, b_ih0, b_hh0,
        wb_ih1, wb_hh1, b_ih1, b_hh1,
        h0a, h0b, h1a, h1b, c0, c1, bar_dec);
}

// Round 7
// 13632.452 us; speedup vs baseline: 2.1762x; 2.1762x over previous
//
#include <hip/hip_runtime.h>
#include <hip/hip_bf16.h>

#define B_SZ 1024
#define T_ENC 384
#define T_DEC 128
#define I_SZ 128
#define H_SZ 512

typedef __attribute__((ext_vector_type(8))) short short8;
typedef __attribute__((ext_vector_type(4))) float floatx4;
typedef unsigned short ushort_t;
typedef unsigned long long u64;

__device__ __forceinline__ ushort_t f2bf(float x) {
    union { float f; unsigned int i; } v; v.f = x;
    unsigned int u = v.i;
    unsigned int r = (u + 0x7fffu + ((u >> 16) & 1u)) >> 16;
    return (ushort_t)r;
}
__device__ __forceinline__ float sigm(float x) { return 1.0f / (1.0f + __expf(-x)); }

// agent-coherent 8B load (bypasses possibly-stale per-XCD L2; served at coherence point)
__device__ __forceinline__ u64 ald8(const ushort_t* p) {
    return __hip_atomic_load((const u64*)(const void*)p, __ATOMIC_RELAXED, __HIP_MEMORY_SCOPE_AGENT);
}

// Bounded relaxed spin with fence fallback (hang-proof; fallback never fires when the
// relaxed-visibility model holds — validated round 4).
__device__ __forceinline__ void spin_ge(unsigned* p, unsigned tgt) {
    int n = 0;
    while (__hip_atomic_load(p, __ATOMIC_RELAXED, __HIP_MEMORY_SCOPE_AGENT) < tgt) {
        __builtin_amdgcn_s_sleep(2);
        if (++n == (1 << 13)) { __threadfence(); n = 0; }
    }
}

// Fence-free monotone tree barrier (validated round 4: correct, no L2 invalidation).
#define BLINE 64   // u32 per line (256B)
__device__ __forceinline__ void gbar(unsigned* bar, int bid, int nb, unsigned& step) {
    asm volatile("s_waitcnt vmcnt(0) lgkmcnt(0)" ::: "memory");   // all waves: publish h
    __syncthreads();
    if (threadIdx.x == 0) {
        const unsigned s1 = step + 1;
        const int grp = bid >> 3;
        const unsigned ngrp = (unsigned)(nb >> 3);
        unsigned* gcnt = bar + (size_t)grp * BLINE;
        unsigned* gsig = gcnt + 1;
        unsigned* rcnt = bar + (size_t)ngrp * BLINE;
        unsigned old = __hip_atomic_fetch_add(gcnt, 1u, __ATOMIC_RELAXED, __HIP_MEMORY_SCOPE_AGENT);
        if (old == 8u * s1 - 1u) {            // last arrival of this group
            unsigned rold = __hip_atomic_fetch_add(rcnt, 1u, __ATOMIC_RELAXED, __HIP_MEMORY_SCOPE_AGENT);
            if (rold != ngrp * s1 - 1u)
                spin_ge(rcnt, ngrp * s1);
            __hip_atomic_store(gsig, s1, __ATOMIC_RELAXED, __HIP_MEMORY_SCOPE_AGENT);
        } else {
            spin_ge(gsig, s1);
        }
    }
    step += 1;
    __syncthreads();
}

// fp32 -> bf16 bulk convert (weights, once per launch). n % 1024 == 0.
__global__ __launch_bounds__(256) void cvt_f32_bf16(
    const float* __restrict__ src, ushort_t* __restrict__ dst, int n)
{
    int i = (blockIdx.x * 256 + threadIdx.x) * 4;
    if (i < n) {
        float4 v = *(const float4*)(src + i);
        short4 s = { (short)f2bf(v.x), (short)f2bf(v.y), (short)f2bf(v.z), (short)f2bf(v.w) };
        *(short4*)(dst + i) = s;
    }
}

// dec_in(t=0) = bf16(x[:, -1, :])
__global__ void copy_last(const float* __restrict__ x, ushort_t* __restrict__ dst)
{
    int i = blockIdx.x * 256 + threadIdx.x;           // 0 .. 131071
    int b = i >> 7, k = i & 127;
    dst[i] = f2bf(x[((size_t)b * T_ENC + (T_ENC - 1)) * I_SZ + k]);
}

#define BM 64
#define BN 32
#define KC 64
#define LDSW (KC + 8)    // 72 shorts: 144B row stride, 16B-aligned, breaks bank stride
#define DLW  (I_SZ + 8)  // 136 shorts: DecIn stride

// XCD-aware swizzle: pin 2 col-groups per XCD so each XCD's weight slice (~832 KB)
// stays L2-resident across the persistent run.
__device__ __forceinline__ void tile_of(int bid, int& row0, int& col0) {
    int xcd = bid & 7, q = bid >> 3;          // q in [0,32)
    int cgp = xcd * 2 + (q & 1);              // col-group 0..15
    int rg = q >> 1;                          // row-group 0..15
    row0 = rg * BM; col0 = cgp * BN;
}

__device__ __forceinline__ void load_bias(
    const float* bih, const float* bhh, int col0, int l15, float (&bs)[4][2])
{
#pragma unroll
    for (int g = 0; g < 4; ++g)
#pragma unroll
        for (int n = 0; n < 2; ++n) {
            int gcol = col0 + n * 16 + l15;
            bs[g][n] = bih[g * H_SZ + gcol] + bhh[g * H_SZ + gcol];
        }
}

// One LSTM cell step for a 64row x (4 gates x 32)col tile; c and biases in registers.
// AMODE: 0 = A1 bf16 global h-buffer (agent loads), 1 = A1 fp32 global x (cached),
//        2 = A1 in LDS (DecIn, stride DLW).
// 1-deep register prefetch with FLAT NAMED registers (no arrays, no lambdas — rule
// #20: arrays/lambda-captures demote to scratch; round-6's 5.7 GB write pathology).
// Chunk kb+1's global loads are issued right after the barrier and fly during kb's
// MFMAs. Weights: plain cached loads (L2-resident); h: agent loads (L2 bypass).
template<int AMODE>
__device__ __forceinline__ void cell_step(
    int row0, int col0,
    const void* A1v, int lda1, int K1,
    const ushort_t* W1, const ushort_t* A2, const ushort_t* W2,
    const float (&bs)[4][2], float (&creg)[2][4],
    ushort_t* h_out, short* As, short* Ws)
{
    const int tid  = threadIdx.x;
    const int wave = tid >> 6;
    const int lane = tid & 63;
    const int quad = lane >> 4;
    const int l15  = lane & 15;
    const int sr   = tid >> 3;     // staging row 0..31 (+32 for second half)
    const int scch = tid & 7;      // staging 16B chunk

    floatx4 acc[4][2];
#pragma unroll
    for (int g = 0; g < 4; ++g)
#pragma unroll
        for (int n = 0; n < 2; ++n)
            acc[g][n] = (floatx4){0.f, 0.f, 0.f, 0.f};

    // flat named prefetch registers
    u64 pa0 = 0, pa1 = 0, pa2 = 0, pa3 = 0;                 // A bf16 path (2x16B)
    floatx4 px0 = {}, px1 = {}, px2 = {}, px3 = {};         // A fp32 path (4x16B)
    int4 pw0, pw1, pw2, pw3;                                 // W path (4x16B)

#define LOAD_W_(kb_) do {                                                          \
    const ushort_t* wsrc_; int wld_;                                               \
    if ((kb_) < K1) { wsrc_ = W1 + (kb_);        wld_ = K1;  }                     \
    else            { wsrc_ = W2 + ((kb_) - K1); wld_ = H_SZ; }                    \
    pw0 = *(const int4*)(const void*)(wsrc_ + (size_t)(0 * H_SZ + col0 + sr) * wld_ + scch * 8); \
    pw1 = *(const int4*)(const void*)(wsrc_ + (size_t)(1 * H_SZ + col0 + sr) * wld_ + scch * 8); \
    pw2 = *(const int4*)(const void*)(wsrc_ + (size_t)(2 * H_SZ + col0 + sr) * wld_ + scch * 8); \
    pw3 = *(const int4*)(const void*)(wsrc_ + (size_t)(3 * H_SZ + col0 + sr) * wld_ + scch * 8); \
  } while (0)

#define LOAD_AX_(kb_) do {                                                         \
    const float* af_ = (const float*)A1v + (kb_);                                  \
    px0 = *(const floatx4*)(const void*)(af_ + (size_t)(row0 + (tid >> 4) +  0) * lda1 + (tid & 15) * 4); \
    px1 = *(const floatx4*)(const void*)(af_ + (size_t)(row0 + (tid >> 4) + 16) * lda1 + (tid & 15) * 4); \
    px2 = *(const floatx4*)(const void*)(af_ + (size_t)(row0 + (tid >> 4) + 32) * lda1 + (tid & 15) * 4); \
    px3 = *(const floatx4*)(const void*)(af_ + (size_t)(row0 + (tid >> 4) + 48) * lda1 + (tid & 15) * 4); \
  } while (0)

#define LOAD_AH_(kb_) do {                                                         \
    const ushort_t* ab_; int ald_;                                                 \
    if ((kb_) < K1) { ab_ = (const ushort_t*)A1v + (kb_); ald_ = lda1; }           \
    else            { ab_ = A2 + ((kb_) - K1);            ald_ = H_SZ; }           \
    const ushort_t* s0_ = ab_ + (size_t)(row0 + sr)      * ald_ + scch * 8;        \
    const ushort_t* s1_ = ab_ + (size_t)(row0 + sr + 32) * ald_ + scch * 8;        \
    pa0 = ald8(s0_); pa1 = ald8(s0_ + 4);                                          \
    pa2 = ald8(s1_); pa3 = ald8(s1_ + 4);                                          \
  } while (0)

    const int KT = K1 + H_SZ;
    if (AMODE == 1)      LOAD_AX_(0);
    else if (AMODE == 0) LOAD_AH_(0);
    LOAD_W_(0);

    for (int kb = 0; kb < KT; kb += KC) {
        // ---- ds_write current prefetched regs ----
        if (AMODE == 1 && kb < K1) {
            short4 s0 = { (short)f2bf(px0.x), (short)f2bf(px0.y), (short)f2bf(px0.z), (short)f2bf(px0.w) };
            short4 s1 = { (short)f2bf(px1.x), (short)f2bf(px1.y), (short)f2bf(px1.z), (short)f2bf(px1.w) };
            short4 s2 = { (short)f2bf(px2.x), (short)f2bf(px2.y), (short)f2bf(px2.z), (short)f2bf(px2.w) };
            short4 s3 = { (short)f2bf(px3.x), (short)f2bf(px3.y), (short)f2bf(px3.z), (short)f2bf(px3.w) };
            *(short4*)(void*)&As[((tid >> 4) +  0) * LDSW + (tid & 15) * 4] = s0;
            *(short4*)(void*)&As[((tid >> 4) + 16) * LDSW + (tid & 15) * 4] = s1;
            *(short4*)(void*)&As[((tid >> 4) + 32) * LDSW + (tid & 15) * 4] = s2;
            *(short4*)(void*)&As[((tid >> 4) + 48) * LDSW + (tid & 15) * 4] = s3;
        } else if (!(AMODE == 2 && kb < K1)) {
            u64* d0 = (u64*)(void*)&As[sr * LDSW + scch * 8];
            d0[0] = pa0; d0[1] = pa1;
            u64* d1 = (u64*)(void*)&As[(sr + 32) * LDSW + scch * 8];
            d1[0] = pa2; d1[1] = pa3;
        }
        *(int4*)(void*)&Ws[(0 * 32 + sr) * LDSW + scch * 8] = pw0;
        *(int4*)(void*)&Ws[(1 * 32 + sr) * LDSW + scch * 8] = pw1;
        *(int4*)(void*)&Ws[(2 * 32 + sr) * LDSW + scch * 8] = pw2;
        *(int4*)(void*)&Ws[(3 * 32 + sr) * LDSW + scch * 8] = pw3;
        __syncthreads();

        // ---- issue next-chunk global loads (fly during MFMAs below) ----
        const int kbn = kb + KC;
        if (kbn < KT) {
            if (AMODE == 1 && kbn < K1) LOAD_AX_(kbn);
            else if (!(AMODE == 2 && kbn < K1)) LOAD_AH_(kbn);
            LOAD_W_(kbn);
        }

        // ---- compute current chunk from LDS ----
#pragma unroll
        for (int ks = 0; ks < 2; ++ks) {
            const int ko = ks * 32 + quad * 8;
            short8 a;
            if (AMODE == 2 && kb < K1)
                a = *(const short8*)(const void*)&((const short*)A1v)[(wave * 16 + l15) * DLW + kb + ko];
            else
                a = *(const short8*)(const void*)&As[(wave * 16 + l15) * LDSW + ko];
#pragma unroll
            for (int g = 0; g < 4; ++g)
#pragma unroll
                for (int n = 0; n < 2; ++n) {
                    short8 b = *(const short8*)(const void*)&Ws[(g * BN + n * 16 + l15) * LDSW + ko];
                    acc[g][n] = __builtin_amdgcn_mfma_f32_16x16x32_bf16(a, b, acc[g][n], 0, 0, 0);
                }
        }
        __syncthreads();
    }
#undef LOAD_W_
#undef LOAD_AX_
#undef LOAD_AH_

#pragma unroll
    for (int n = 0; n < 2; ++n) {
        const int gcol = col0 + n * 16 + l15;
#pragma unroll
        for (int r = 0; r < 4; ++r) {
            const int grow = row0 + wave * 16 + quad * 4 + r;
            const float zi = acc[0][n][r] + bs[0][n];
            const float zf = acc[1][n][r] + bs[1][n];
            const float zg = acc[2][n][r] + bs[2][n];
            const float zo = acc[3][n][r] + bs[3][n];
            const float cn = sigm(zf) * creg[n][r] + sigm(zi) * tanhf(zg);
            creg[n][r] = cn;
            const float hv = sigm(zo) * tanhf(cn);
            const float hnb = __shfl_xor(hv, 1);
            if ((lane & 1) == 0) {   // paired lanes: one 32-bit agent store per 2 cols
                unsigned p = (unsigned)f2bf(hv) | ((unsigned)f2bf(hnb) << 16);
                __hip_atomic_store((unsigned*)(void*)&h_out[(size_t)grow * H_SZ + gcol],
                                   p, __ATOMIC_RELAXED, __HIP_MEMORY_SCOPE_AGENT);
            }
        }
    }
}

// Persistent encoder: 512 blocks (2/CU, all resident).
// Blocks 0..255: L0(t) for t=0..383.  Blocks 256..511: L1(t-1) for t=1..384.
__global__ __launch_bounds__(256, 2) void enc_persist(
    const float* x,
    const ushort_t* Wih0, const ushort_t* Whh0, const float* bih0, const float* bhh0,
    const ushort_t* Wih1, const ushort_t* Whh1, const float* bih1, const float* bhh1,
    ushort_t* h0a, ushort_t* h0b, ushort_t* h1a, ushort_t* h1b,
    float* c0, float* c1, unsigned* bar)
{
    __shared__ short As[BM * LDSW];
    __shared__ short Ws[4 * BN * LDSW];

    const int tid = threadIdx.x;
    const int bid = blockIdx.x;
    const bool isL0 = (bid < 256);
    int row0, col0; tile_of(isL0 ? bid : (bid - 256), row0, col0);
    const int lane = tid & 63, l15 = lane & 15, quad = lane >> 4, wave = tid >> 6;

    float bs[4][2];
    load_bias(isL0 ? bih0 : bih1, isL0 ? bhh0 : bhh1, col0, l15, bs);
    float creg[2][4];
#pragma unroll
    for (int n = 0; n < 2; ++n)
#pragma unroll
        for (int r = 0; r < 4; ++r) creg[n][r] = 0.f;

    ushort_t *h0c = h0a, *h0n = h0b, *h1c = h1a, *h1n = h1b;
    unsigned step = 0;

    for (int t = 0; t <= T_ENC; ++t) {
        if (isL0) {
            if (t < T_ENC)
                cell_step<1>(row0, col0, x + (size_t)t * I_SZ, T_ENC * I_SZ, I_SZ,
                             Wih0, h0c, Whh0, bs, creg, h0n, As, Ws);
        } else {
            if (t > 0)
                cell_step<0>(row0, col0, h0c, H_SZ, H_SZ,
                             Wih1, h1c, Whh1, bs, creg, h1n, As, Ws);
        }
        gbar(bar, bid, 512, step);
        if (t < T_ENC) { ushort_t* tmp = h0c; h0c = h0n; h0n = tmp; }
        if (t > 0)     { ushort_t* tmp = h1c; h1c = h1n; h1n = tmp; }
    }
    // final c states for the decoder (kernel boundary publishes them)
    float* cdst = isL0 ? c0 : c1;
#pragma unroll
    for (int n = 0; n < 2; ++n)
#pragma unroll
        for (int r = 0; r < 4; ++r) {
            int grow = row0 + wave * 16 + quad * 4 + r;
            int gcol = col0 + n * 16 + l15;
            cdst[(size_t)grow * H_SZ + gcol] = creg[n][r];
        }
}

// Persistent decoder: 256 blocks (all resident). Each block owns the same (rg,cg)
// tile of BOTH layers; c0/c1 tiles live in registers the whole run.
// Per step t: [fc(t-1)+out + L0(t)]  barrier  [L1(t)]  barrier.
__global__ __launch_bounds__(256, 2) void dec_persist(
    const ushort_t* dec0, const ushort_t* fcw, const float* fcb, float* out,
    const ushort_t* Wih0, const ushort_t* Whh0, const float* bih0, const float* bhh0,
    const ushort_t* Wih1, const ushort_t* Whh1, const float* bih1, const float* bhh1,
    ushort_t* h0a, ushort_t* h0b, ushort_t* h1a, ushort_t* h1b,
    const float* c0in, const float* c1in, unsigned* bar)
{
    __shared__ short As[BM * LDSW];
    __shared__ short Ws[4 * BN * LDSW];
    __shared__ short DecIn[BM * DLW];

    const int tid = threadIdx.x;
    const int wave = tid >> 6, lane = tid & 63, quad = lane >> 4, l15 = lane & 15;
    const int sr = tid >> 3, scch = tid & 7;
    int row0, col0; tile_of(blockIdx.x, row0, col0);
    const int cgrp = col0 / BN;

    float bs0[4][2], bs1[4][2];
    load_bias(bih0, bhh0, col0, l15, bs0);
    load_bias(bih1, bhh1, col0, l15, bs1);

    float c0reg[2][4], c1reg[2][4];
#pragma unroll
    for (int n = 0; n < 2; ++n)
#pragma unroll
        for (int r = 0; r < 4; ++r) {
            int grow = row0 + wave * 16 + quad * 4 + r;
            int gcol = col0 + n * 16 + l15;
            c0reg[n][r] = c0in[(size_t)grow * H_SZ + gcol];
            c1reg[n][r] = c1in[(size_t)grow * H_SZ + gcol];
        }

    ushort_t *h0c = h0a, *h0n = h0b, *h1c = h1a, *h1n = h1b;
    unsigned step = 0;

    for (int t = 0; t <= T_DEC; ++t) {
        // ---------- phase A: fc(t-1) -> DecIn (+ out(t-1)), then L0(t) ----------
        if (t > 0) {
            float* outp = out + (size_t)(t - 1) * I_SZ;
            floatx4 a2[8];
#pragma unroll
            for (int n = 0; n < 8; ++n) a2[n] = (floatx4){0.f, 0.f, 0.f, 0.f};

            u64 fa0, fa1, fa2, fa3;
            int4 fw0, fw1, fw2, fw3;
#define LOAD_FA_(kb_) do {                                                         \
    const ushort_t* s0_ = h1c + (size_t)(row0 + sr)      * H_SZ + (kb_) + scch * 8; \
    const ushort_t* s1_ = h1c + (size_t)(row0 + sr + 32) * H_SZ + (kb_) + scch * 8; \
    fa0 = ald8(s0_); fa1 = ald8(s0_ + 4);                                          \
    fa2 = ald8(s1_); fa3 = ald8(s1_ + 4);                                          \
  } while (0)
#define LOAD_FW_(kb_) do {                                                         \
    fw0 = *(const int4*)(const void*)(fcw + (size_t)(0 * 32 + sr) * H_SZ + (kb_) + scch * 8); \
    fw1 = *(const int4*)(const void*)(fcw + (size_t)(1 * 32 + sr) * H_SZ + (kb_) + scch * 8); \
    fw2 = *(const int4*)(const void*)(fcw + (size_t)(2 * 32 + sr) * H_SZ + (kb_) + scch * 8); \
    fw3 = *(const int4*)(const void*)(fcw + (size_t)(3 * 32 + sr) * H_SZ + (kb_) + scch * 8); \
  } while (0)
            LOAD_FA_(0); LOAD_FW_(0);

            for (int kb = 0; kb < H_SZ; kb += KC) {
                u64* d0 = (u64*)(void*)&As[sr * LDSW + scch * 8];
                d0[0] = fa0; d0[1] = fa1;
                u64* d1 = (u64*)(void*)&As[(sr + 32) * LDSW + scch * 8];
                d1[0] = fa2; d1[1] = fa3;
                *(int4*)(void*)&Ws[(0 * 32 + sr) * LDSW + scch * 8] = fw0;
                *(int4*)(void*)&Ws[(1 * 32 + sr) * LDSW + scch * 8] = fw1;
                *(int4*)(void*)&Ws[(2 * 32 + sr) * LDSW + scch * 8] = fw2;
                *(int4*)(void*)&Ws[(3 * 32 + sr) * LDSW + scch * 8] = fw3;
                __syncthreads();

                const int kbn = kb + KC;
                if (kbn < H_SZ) { LOAD_FA_(kbn); LOAD_FW_(kbn); }

#pragma unroll
                for (int ks = 0; ks < 2; ++ks) {
                    const int ko = ks * 32 + quad * 8;
                    short8 a = *(const short8*)(const void*)&As[(wave * 16 + l15) * LDSW + ko];
#pragma unroll
                    for (int n = 0; n < 8; ++n) {
                        short8 b = *(const short8*)(const void*)&Ws[(n * 16 + l15) * LDSW + ko];
                        a2[n] = __builtin_amdgcn_mfma_f32_16x16x32_bf16(a, b, a2[n], 0, 0, 0);
                    }
                }
                __syncthreads();
            }
#undef LOAD_FA_
#undef LOAD_FW_
#pragma unroll
            for (int n = 0; n < 8; ++n) {
                const int col = n * 16 + l15;
                const float bias = fcb[col];
#pragma unroll
                for (int r = 0; r < 4; ++r) {
                    const int lrow = wave * 16 + quad * 4 + r;
                    const float v = a2[n][r] + bias;
                    DecIn[lrow * DLW + col] = (short)f2bf(v);
                    if (cgrp == 0)
                        outp[(size_t)(row0 + lrow) * T_DEC * I_SZ + col] = v;
                }
            }
        } else {
            // t==0: dec_in from global bf16 buffer (written by an earlier dispatch)
#pragma unroll
            for (int it = 0; it < 4; ++it) {
                int idx = tid + it * 256;              // 0..1023
                int r = idx >> 4, cch = idx & 15;
                int4 v = *(const int4*)(const void*)(dec0 + (size_t)(row0 + r) * I_SZ + cch * 8);
                *(int4*)(void*)&DecIn[r * DLW + cch * 8] = v;
            }
        }
        __syncthreads();

        if (t < T_DEC)
            cell_step<2>(row0, col0, (const void*)DecIn, DLW, I_SZ,
                         Wih0, h0c, Whh0, bs0, c0reg, h0n, As, Ws);
        gbar(bar, blockIdx.x, 256, step);

        // ---------- phase B: L1(t) ----------
        if (t < T_DEC) {
            cell_step<0>(row0, col0, h0n, H_SZ, H_SZ,
                         Wih1, h1c, Whh1, bs1, c1reg, h1n, As, Ws);
            gbar(bar, blockIdx.x, 256, step);
            { ushort_t* tmp = h0c; h0c = h0n; h0n = tmp; }
            { ushort_t* tmp = h1c; h1c = h1n; h1n = tmp; }
        }
    }
}

extern "C" void kernel_launch(void* const* d_in, const int* in_sizes, int n_in,
                              void* d_out, int out_size, void* d_ws, size_t ws_size,
                              hipStream_t stream)
{
    (void)in_sizes; (void)n_in; (void)out_size; (void)ws_size;
    const float* x     = (const float*)d_in[0];
    const float* W_ih0 = (const float*)d_in[1];
    const float* W_hh0 = (const float*)d_in[2];
    const float* b_ih0 = (const float*)d_in[3];
    const float* b_hh0 = (const float*)d_in[4];
    const float* W_ih1 = (const float*)d_in[5];
    const float* W_hh1 = (const float*)d_in[6];
    const float* b_ih1 = (const float*)d_in[7];
    const float* b_hh1 = (const float*)d_in[8];
    const float* fc_w  = (const float*)d_in[9];
    const float* fc_b  = (const float*)d_in[10];
    float* out = (float*)d_out;

    const int NW_IH0 = 4 * H_SZ * I_SZ;   // 262144
    const int NW_HH  = 4 * H_SZ * H_SZ;   // 1048576
    const int NW_FC  = I_SZ * H_SZ;       // 65536
    char* w = (char*)d_ws;
    ushort_t* wb_ih0 = (ushort_t*)w;  w += (size_t)NW_IH0 * 2;
    ushort_t* wb_hh0 = (ushort_t*)w;  w += (size_t)NW_HH  * 2;
    ushort_t* wb_ih1 = (ushort_t*)w;  w += (size_t)NW_HH  * 2;
    ushort_t* wb_hh1 = (ushort_t*)w;  w += (size_t)NW_HH  * 2;
    ushort_t* wb_fc  = (ushort_t*)w;  w += (size_t)NW_FC  * 2;
    const size_t HB2 = (size_t)B_SZ * H_SZ * 2;    // 1 MB bf16
    const size_t HB4 = (size_t)B_SZ * H_SZ * 4;    // 2 MB fp32
    ushort_t* h0a = (ushort_t*)w;  w += HB2;
    ushort_t* h0b = (ushort_t*)w;  w += HB2;
    ushort_t* h1a = (ushort_t*)w;  w += HB2;
    ushort_t* h1b = (ushort_t*)w;  w += HB2;
    float*    c0  = (float*)w;     w += HB4;
    float*    c1  = (float*)w;     w += HB4;
    ushort_t* dec0 = (ushort_t*)w; w += (size_t)B_SZ * I_SZ * 2;
    // barrier regions: enc = 64 groups + root = 65 lines; dec = 32 groups + root = 33
    unsigned* bar_enc = (unsigned*)w;              // 65 * 256B
    unsigned* bar_dec = bar_enc + 65 * 64;         // 33 * 256B
    const size_t BAR_BYTES = (65 + 33) * 256;
    w += BAR_BYTES;

    cvt_f32_bf16<<<NW_IH0 / 1024, 256, 0, stream>>>(W_ih0, wb_ih0, NW_IH0);
    cvt_f32_bf16<<<NW_HH  / 1024, 256, 0, stream>>>(W_hh0, wb_hh0, NW_HH);
    cvt_f32_bf16<<<NW_HH  / 1024, 256, 0, stream>>>(W_ih1, wb_ih1, NW_HH);
    cvt_f32_bf16<<<NW_HH  / 1024, 256, 0, stream>>>(W_hh1, wb_hh1, NW_HH);
    cvt_f32_bf16<<<NW_FC  / 1024, 256, 0, stream>>>(fc_w,  wb_fc,  NW_FC);

    hipMemsetAsync(h0a, 0, HB2, stream);
    hipMemsetAsync(h1a, 0, HB2, stream);
    hipMemsetAsync(bar_enc, 0, BAR_BYTES, stream);
    copy_last<<<512, 256, 0, stream>>>(x, dec0);

    // whole encoder: ONE launch, fence-free tree barrier between steps
    enc_persist<<<512, 256, 0, stream>>>(
        x, wb_ih0, wb_hh0, b_ih0, b_hh0,
        wb_ih1, wb_hh1, b_ih1, b_hh1,
        h0a, h0b, h1a, h1b, c0, c1, bar_enc);

    // whole decoder (incl. final fc): ONE launch
    dec_persist<<<256, 256, 0, stream>>>(
        dec0, wb_fc, fc_b, out,
        wb_ih0, wb_hh0, b_ih0, b_hh0,
        wb_ih1, wb_hh1, b_ih1, b_hh1,
        h0a, h0b, h1a, h1b, c0, c1, bar_dec);
}